// Round 6
// baseline (48.179 us; speedup 1.0000x reference)
//
#include <hip/hip_runtime.h>

// out[b,n,:] = tables[template_id[b], atom_role[b,n], :]   (all fp32)
// B=4096, N=128, T=64, R=16, D=128.
// Write-BW-bound: 256 MiB streaming write; fill-kernel ceiling ~7 TB/s.
//
// R6 geometry: one block per batch b (UNROLL=16 x BLOCK=256 = 4096 float4 =
// exactly one batch's output). template_id[b] is block-uniform -> scalar
// s_load; roles are 16 broadcast L1 hits; block writes contiguous 64 KB.

constexpr int B = 4096;
constexpr int N = 128;
constexpr int R = 16;
constexpr int D = 128;
constexpr int BLOCK = 256;
constexpr int ITERS = 16;                      // 4096 float4 per block / 256

typedef float floatx4 __attribute__((ext_vector_type(4)));

__global__ __launch_bounds__(BLOCK) void role_embed_gather(
    const int* __restrict__ template_id,   // [B]
    const int* __restrict__ atom_role,     // [B*N]
    const float* __restrict__ tables,      // [T*R*D]
    floatx4* __restrict__ out)             // [B*N*D/4]
{
    const int b   = blockIdx.x;
    const int tid = threadIdx.x;

    // Block-uniform template id -> compiler emits a scalar load.
    const int t = template_id[b];
    const floatx4* tab = reinterpret_cast<const floatx4*>(tables + t * (R * D));

    const int col = tid & 31;     // float4 column within a D=128 row
    const int r0  = tid >> 5;     // base row offset (0..7)

    // Phase 1: this thread's 16 roles (broadcast L1 hits, independent).
    int rl[ITERS];
#pragma unroll
    for (int k = 0; k < ITERS; ++k)
        rl[k] = atom_role[(b << 7) + (k << 3) + r0];

    // Phase 2+3: 16 independent L2-resident gathers -> 16 contiguous stores.
    floatx4* ob = out + ((size_t)b << 12);   // b * 4096 float4
#pragma unroll
    for (int k = 0; k < ITERS; ++k) {
        const floatx4 v = tab[rl[k] * (D / 4) + col];
        ob[(k << 8) + tid] = v;
    }
}

extern "C" void kernel_launch(void* const* d_in, const int* in_sizes, int n_in,
                              void* d_out, int out_size, void* d_ws, size_t ws_size,
                              hipStream_t stream) {
    const int*   template_id = (const int*)d_in[0];
    const int*   atom_role   = (const int*)d_in[1];
    const float* tables      = (const float*)d_in[2];
    floatx4*     out         = (floatx4*)d_out;

    role_embed_gather<<<B, BLOCK, 0, stream>>>(template_id, atom_role, tables, out);
}

// Round 7
// 47.144 us; speedup vs baseline: 1.0220x; 1.0220x over previous
//
#include <hip/hip_runtime.h>

// out[b,n,:] = tables[template_id[b], atom_role[b,n], :]   (all fp32)
// B=4096, N=128, T=64, R=16, D=128.
// Write-BW-bound. Best so far: R5 (unroll8, 8192 blocks, plain stores) 46.4us.
// R7 = R5 geometry + block-uniform template_id (block = half batch -> one
// scalar s_load instead of 8 per-lane gathers), keeping VGPRs ~50.

constexpr int B = 4096;
constexpr int N = 128;
constexpr int R = 16;
constexpr int D = 128;
constexpr int BLOCK  = 256;
constexpr int UNROLL = 8;
constexpr int F4_PER_BLOCK = BLOCK * UNROLL;      // 2048 f4 = 64 rows = B/2
constexpr int GRID = (B * N * (D / 4)) / F4_PER_BLOCK;  // 8192

typedef float floatx4 __attribute__((ext_vector_type(4)));

__global__ __launch_bounds__(BLOCK) void role_embed_gather(
    const int* __restrict__ template_id,   // [B]
    const int* __restrict__ atom_role,     // [B*N]
    const float* __restrict__ tables,      // [T*R*D]
    floatx4* __restrict__ out)             // [B*N*D/4]
{
    const int tid = threadIdx.x;
    const int blk = blockIdx.x;

    // Block covers rows [blk*64, blk*64+64) -> batch b = blk>>1 (uniform).
    const int t = template_id[blk >> 1];           // scalar s_load
    const floatx4* tab =
        reinterpret_cast<const floatx4*>(tables + t * (R * D));

    const int col  = tid & 31;                     // f4 column in D=128 row
    const int row0 = blk * 64 + (tid >> 5);        // this thread's base row

    // Phase 1: 8 independent role loads (32-lane broadcast, L1/L2-hit).
    int rl[UNROLL];
#pragma unroll
    for (int k = 0; k < UNROLL; ++k)
        rl[k] = atom_role[row0 + k * 8];

    // Phase 2+3: 8 independent L2-resident gathers -> 8 contiguous stores.
    floatx4* ob = out + (size_t)blk * F4_PER_BLOCK;
#pragma unroll
    for (int k = 0; k < UNROLL; ++k) {
        const floatx4 v = tab[rl[k] * (D / 4) + col];
        ob[k * BLOCK + tid] = v;
    }
}

extern "C" void kernel_launch(void* const* d_in, const int* in_sizes, int n_in,
                              void* d_out, int out_size, void* d_ws, size_t ws_size,
                              hipStream_t stream) {
    const int*   template_id = (const int*)d_in[0];
    const int*   atom_role   = (const int*)d_in[1];
    const float* tables      = (const float*)d_in[2];
    floatx4*     out         = (floatx4*)d_out;

    role_embed_gather<<<GRID, BLOCK, 0, stream>>>(template_id, atom_role, tables, out);
}